// Round 17
// baseline (506.755 us; speedup 1.0000x reference)
//
#include <hip/hip_runtime.h>
#include <hip/hip_bf16.h>
#include <math.h>

#define DD 256
#define BUCKET_SHIFT 9      // 512 rows per bucket
#define BROWS 512
#define CHUNK_A 4096        // edges per partition block
#define CBLK_SHIFT 13

typedef __attribute__((ext_vector_type(8))) short short8;
typedef __attribute__((ext_vector_type(4))) float f32x4;
typedef __attribute__((ext_vector_type(2))) float f32x2;

__device__ __forceinline__ float gelu_exact(float x) {
    return 0.5f * x * (1.0f + erff(x * 0.70710678118654752f));
}
__device__ __forceinline__ float b2f(unsigned short u) {
    unsigned int v = ((unsigned int)u) << 16;
    return __builtin_bit_cast(float, v);
}
__device__ __forceinline__ unsigned short f2b(float f) {
    __hip_bfloat16 h = __float2bfloat16(f);   // RNE
    return __builtin_bit_cast(unsigned short, h);
}

// decode 8 fp8 (uint2) -> 8 f32 via packed HW converts (same decode path as scalar)
__device__ __forceinline__ void f8x8_to_f32(uint2 u, float* o) {
    f32x2 p0 = __builtin_amdgcn_cvt_pk_f32_fp8((int)u.x, false);
    f32x2 p1 = __builtin_amdgcn_cvt_pk_f32_fp8((int)u.x, true);
    f32x2 p2 = __builtin_amdgcn_cvt_pk_f32_fp8((int)u.y, false);
    f32x2 p3 = __builtin_amdgcn_cvt_pk_f32_fp8((int)u.y, true);
    o[0] = p0.x; o[1] = p0.y; o[2] = p1.x; o[3] = p1.y;
    o[4] = p2.x; o[5] = p2.y; o[6] = p3.x; o[7] = p3.y;
}

// ---------------- CSR build ----------------
__global__ __launch_bounds__(256) void part_hist(const int* __restrict__ rows,
                                                 int* __restrict__ bh,
                                                 int nnz, int NB, int nblkA) {
    int rel = blockIdx.y, blk = blockIdx.x;
    __shared__ int h[128];
    for (int b = threadIdx.x; b < NB; b += 256) h[b] = 0;
    __syncthreads();
    int base = blk * CHUNK_A;
    #pragma unroll
    for (int k = 0; k < CHUNK_A / 256; ++k) {
        int i = base + k * 256 + threadIdx.x;
        if (i < nnz) atomicAdd(&h[rows[(size_t)rel * nnz + i] >> BUCKET_SHIFT], 1);
    }
    __syncthreads();
    for (int b = threadIdx.x; b < NB; b += 256)
        bh[((size_t)(rel * NB + b)) * nblkA + blk] = h[b];
}

__global__ __launch_bounds__(256) void scan1(const int* __restrict__ cnt,
                                             int* __restrict__ rp, int* __restrict__ psum,
                                             int N, int nchunks) {
    int rel = blockIdx.x / nchunks;
    int chunk = blockIdx.x % nchunks;
    const int* c = cnt + (size_t)rel * N;
    int* out = rp + (size_t)rel * (N + 1);
    int tid = threadIdx.x, lane = tid & 63, wv = tid >> 6;
    __shared__ int wsum[4];
    int base = chunk * 1024 + tid * 4;
    int v[4];
    if (base + 3 < N) {
        int4 t4 = *(const int4*)(c + base);
        v[0] = t4.x; v[1] = t4.y; v[2] = t4.z; v[3] = t4.w;
    } else {
        #pragma unroll
        for (int q = 0; q < 4; ++q) v[q] = (base + q < N) ? c[base + q] : 0;
    }
    int tsum = v[0] + v[1] + v[2] + v[3];
    int x = tsum;
    #pragma unroll
    for (int off = 1; off < 64; off <<= 1) {
        int t = __shfl_up(x, off, 64);
        if (lane >= off) x += t;
    }
    if (lane == 63) wsum[wv] = x;
    __syncthreads();
    int woff = 0;
    #pragma unroll
    for (int k = 0; k < 4; ++k) if (k < wv) woff += wsum[k];
    int run = woff + x - tsum;
    #pragma unroll
    for (int q = 0; q < 4; ++q) {
        if (base + q < N) out[base + q] = run;
        run += v[q];
    }
    if (tid == 255) psum[rel * nchunks + chunk] = woff + x;
}

__global__ __launch_bounds__(256) void scan2(int* __restrict__ psum, int* __restrict__ rp,
                                             int N, int nchunks, int R) {
    int rel = threadIdx.x >> 6, lane = threadIdx.x & 63;
    if (rel >= R) return;
    int v = (lane < nchunks) ? psum[rel * nchunks + lane] : 0;
    int x = v;
    #pragma unroll
    for (int off = 1; off < 64; off <<= 1) {
        int t = __shfl_up(x, off, 64);
        if (lane >= off) x += t;
    }
    if (lane < nchunks) psum[rel * nchunks + lane] = x - v;
    if (lane == 63) rp[(size_t)rel * (N + 1) + N] = x;
}

__global__ __launch_bounds__(256) void scan3(int* __restrict__ rp, const int* __restrict__ psum,
                                             int N, int nchunks) {
    int rel = blockIdx.y;
    int i = blockIdx.x * 256 + threadIdx.x;
    if (i >= N) return;
    rp[(size_t)rel * (N + 1) + i] += psum[rel * nchunks + (i >> 10)];
}

__global__ __launch_bounds__(256) void part_scatter(
    const int* __restrict__ rows, const int* __restrict__ cols,
    const float* __restrict__ vals, const int* __restrict__ bhs,
    int2* __restrict__ staged, int nnz, int NB, int nblkA) {
    int rel = blockIdx.y, blk = blockIdx.x;
    __shared__ int cur[128];
    for (int b = threadIdx.x; b < NB; b += 256)
        cur[b] = bhs[((size_t)(rel * NB + b)) * nblkA + blk];
    __syncthreads();
    int base = blk * CHUNK_A;
    #pragma unroll
    for (int k = 0; k < CHUNK_A / 256; ++k) {
        int i = base + k * 256 + threadIdx.x;
        if (i < nnz) {
            int r = rows[(size_t)rel * nnz + i];
            unsigned c = (unsigned)cols[(size_t)rel * nnz + i];
            float v = vals[(size_t)rel * nnz + i];
            int pos = atomicAdd(&cur[r >> BUCKET_SHIFT], 1);
            int2 pr;
            pr.x = (int)(((unsigned)r << 16) | c);
            pr.y = __float_as_int(v);
            staged[pos] = pr;
        }
    }
}

// single-pass (row x colblock) counting sort (r13, verified)
__global__ __launch_bounds__(512) void bucket_build(
    const int2* __restrict__ staged, const int* __restrict__ bhs,
    int* __restrict__ rp, int2* __restrict__ spair,
    int nnz, int N, int NB, int nblkA, int R) {
    int rel = blockIdx.y, b = blockIdx.x;
    int start = bhs[((size_t)(rel * NB + b)) * nblkA];
    int nb1 = rel * NB + b + 1;
    int end = (nb1 < R * NB) ? bhs[(size_t)nb1 * nblkA] : R * nnz;
    int csr_base = start - rel * nnz;
    int rowbase = b << BUCKET_SHIFT;
    __shared__ int cnt2[BROWS * 8];
    __shared__ int wsum[8];
    int t = threadIdx.x, lane = t & 63, wv = t >> 6;
    #pragma unroll
    for (int q = 0; q < 8; ++q) cnt2[t + q * BROWS] = 0;
    __syncthreads();
    for (int i = start + t; i < end; i += 512) {
        unsigned p = (unsigned)staged[i].x;
        int rb = (int)(p >> 16) - rowbase;
        int cb = (int)(p & 0xFFFFu) >> CBLK_SHIFT;
        atomicAdd(&cnt2[rb * 8 + cb], 1);
    }
    __syncthreads();
    int c[8];
    int v = 0;
    #pragma unroll
    for (int q = 0; q < 8; ++q) { c[q] = cnt2[t * 8 + q]; v += c[q]; }
    int x = v;
    #pragma unroll
    for (int off = 1; off < 64; off <<= 1) {
        int tt = __shfl_up(x, off, 64);
        if (lane >= off) x += tt;
    }
    if (lane == 63) wsum[wv] = x;
    __syncthreads();
    int woff = 0;
    #pragma unroll
    for (int k = 0; k < 8; ++k) if (k < wv) woff += wsum[k];
    int excl = woff + x - v;
    __syncthreads();
    int run = excl;
    #pragma unroll
    for (int q = 0; q < 8; ++q) { cnt2[t * 8 + q] = run; run += c[q]; }
    int gr = rowbase + t;
    if (gr <= N) rp[(size_t)rel * (N + 1) + gr] = csr_base + excl;
    __syncthreads();
    for (int i = start + t; i < end; i += 512) {
        int2 s = staged[i];
        unsigned p = (unsigned)s.x;
        int rb = (int)(p >> 16) - rowbase;
        int col = (int)(p & 0xFFFFu);
        int pos = atomicAdd(&cnt2[rb * 8 + (col >> CBLK_SHIFT)], 1);
        int2 pr;
        pr.x = col;
        pr.y = s.y;
        spair[(size_t)rel * nnz + csr_base + pos] = pr;
    }
}

// ---------------- tiled W transpose+cast ----------------
__global__ __launch_bounds__(256) void transpose_cast_w(
    const float* __restrict__ Wp, const float* __restrict__ Wv,
    unsigned short* __restrict__ wt) {
    __shared__ float tile[32][33];
    int m = blockIdx.y;
    int tb = blockIdx.x;
    int k0 = (tb & 7) * 32, n0 = (tb >> 3) * 32;
    const float* W = (m == 0) ? Wp : (Wv + (size_t)(m - 1) * 65536);
    int tx = threadIdx.x & 31, ty = threadIdx.x >> 5;
    #pragma unroll
    for (int i = 0; i < 4; ++i)
        tile[ty + 8 * i][tx] = W[(size_t)(k0 + ty + 8 * i) * 256 + n0 + tx];
    __syncthreads();
    #pragma unroll
    for (int i = 0; i < 4; ++i)
        wt[(size_t)m * 65536 + (size_t)(n0 + ty + 8 * i) * 256 + k0 + tx] =
            f2b(tile[tx][ty + 8 * i]);
}

// ---------------- bf16 -> fp8 e4m3 cast (HW RNE via v_cvt_pk_fp8_f32) ----------------
__global__ __launch_bounds__(256) void cast_f8(const unsigned short* __restrict__ xb,
                                               unsigned char* __restrict__ xf, long n8) {
    long i = (long)blockIdx.x * 256 + threadIdx.x;   // 8 elems per thread
    if (i >= n8) return;
    short8 v = *(const short8*)(xb + i * 8);
    float f[8];
    #pragma unroll
    for (int k = 0; k < 8; ++k) f[k] = b2f((unsigned short)v[k]);
    int d0 = __builtin_amdgcn_cvt_pk_fp8_f32(f[0], f[1], 0, false);
    d0 = __builtin_amdgcn_cvt_pk_fp8_f32(f[2], f[3], d0, true);
    int d1 = __builtin_amdgcn_cvt_pk_fp8_f32(f[4], f[5], 0, false);
    d1 = __builtin_amdgcn_cvt_pk_fp8_f32(f[6], f[7], d1, true);
    *(uint2*)(xf + i * 8) = make_uint2((unsigned)d0, (unsigned)d1);
}

// ---------------- W-in-LDS MFMA GEMM -> LN -> GELU (512 threads) ----------------
// All 8 A-fragments prefetched before the MFMA loop: at 2 waves/SIMD (128 KB LDS
// forces 1 block/CU), deep ILP on the A-loads is the only latency hiding available.
template <bool A_BF16, bool OUT_BF16>
__global__ __launch_bounds__(512) void gemm_wlds(
    const void* __restrict__ Aptr, const unsigned short* __restrict__ Wt,
    const float* __restrict__ bias, const float* __restrict__ gamma,
    const float* __restrict__ beta, void* __restrict__ outp, int M, int ntiles,
    size_t aStrideB, size_t wStride, int pStride, size_t oStrideB)
{
    __shared__ __align__(16) unsigned short Wl[256 * 256];
    __shared__ float Pb[DD], Pg[DD], Pe[DD];
    const int rel = blockIdx.y;
    const char* Abase = (const char*)Aptr + (size_t)rel * aStrideB;
    char* Obase = (char*)outp + (size_t)rel * oStrideB;
    const unsigned short* Wtr = Wt + (size_t)rel * wStride;
    const int tid = threadIdx.x;
    const int lane = tid & 63;
    const int wv = tid >> 6;
    if (tid < DD) {
        Pb[tid] = bias[rel * pStride + tid];
        Pg[tid] = gamma[rel * pStride + tid];
        Pe[tid] = beta[rel * pStride + tid];
    }
    {
        int n = tid >> 1;
        int half = tid & 1;
        const unsigned short* src = Wtr + (size_t)n * DD + half * 128;
        #pragma unroll
        for (int c = 0; c < 16; ++c) {
            int c16 = half * 16 + c;
            short8 v = *(const short8*)(src + c * 8);
            *(short8*)(Wl + n * DD + ((c16 ^ (n & 7)) << 3)) = v;
        }
    }
    __syncthreads();

    const int cl = lane & 15, g = lane >> 4;

    for (int tile = blockIdx.x; tile < ntiles; tile += gridDim.x) {
        const int rbase = tile * 128 + wv * 16;
        const int arow = rbase + cl;
        const bool rok = arow < M;
        f32x4 acc[16];
        #pragma unroll
        for (int j = 0; j < 16; ++j) acc[j] = (f32x4){0.f, 0.f, 0.f, 0.f};

        // prefetch ALL 8 A-fragments (64 VGPR) — 8 loads in flight
        short8 af[8];
        #pragma unroll
        for (int ks = 0; ks < 8; ++ks) af[ks] = (short8){0,0,0,0,0,0,0,0};
        if (rok) {
            if (A_BF16) {
                #pragma unroll
                for (int ks = 0; ks < 8; ++ks)
                    af[ks] = *(const short8*)((const unsigned short*)Abase +
                                (size_t)arow * DD + ks * 32 + g * 8);
            } else {
                float4 fl[16];
                #pragma unroll
                for (int ks = 0; ks < 8; ++ks) {
                    const float* ap = (const float*)Abase + (size_t)arow * DD + ks * 32 + g * 8;
                    fl[2 * ks]     = *(const float4*)ap;
                    fl[2 * ks + 1] = *(const float4*)(ap + 4);
                }
                #pragma unroll
                for (int ks = 0; ks < 8; ++ks) {
                    float4 f0 = fl[2 * ks], f1 = fl[2 * ks + 1];
                    af[ks] = (short8){(short)f2b(f0.x), (short)f2b(f0.y), (short)f2b(f0.z), (short)f2b(f0.w),
                                      (short)f2b(f1.x), (short)f2b(f1.y), (short)f2b(f1.z), (short)f2b(f1.w)};
                }
            }
        }

        #pragma unroll
        for (int ks = 0; ks < 8; ++ks) {
            int c16 = 4 * ks + g;
            #pragma unroll
            for (int j = 0; j < 16; ++j) {
                int n = j * 16 + cl;
                short8 bf = *(const short8*)(Wl + n * DD + ((c16 ^ (n & 7)) << 3));
                acc[j] = __builtin_amdgcn_mfma_f32_16x16x32_bf16(af[ks], bf, acc[j], 0, 0, 0);
            }
        }

        #pragma unroll
        for (int q = 0; q < 4; ++q) {
            float yv[16];
            float s = 0.f, ss = 0.f;
            #pragma unroll
            for (int j = 0; j < 16; ++j) {
                float y = acc[j][q] + Pb[cl + 16 * j];
                yv[j] = y; s += y; ss += y * y;
            }
            #pragma unroll
            for (int off = 1; off < 16; off <<= 1) {
                s  += __shfl_xor(s,  off, 16);
                ss += __shfl_xor(ss, off, 16);
            }
            float mean = s * (1.0f / DD);
            float var  = ss * (1.0f / DD) - mean * mean;
            float rstd = rsqrtf(var + 1e-5f);
            int row = rbase + g * 4 + q;
            if (row < M) {
                #pragma unroll
                for (int j = 0; j < 16; ++j) {
                    int col = cl + 16 * j;
                    float o = gelu_exact((yv[j] - mean) * rstd * Pg[col] + Pe[col]);
                    if (OUT_BF16)
                        ((unsigned short*)Obase)[(size_t)row * DD + col] = f2b(o);
                    else
                        ((float*)Obase)[(size_t)row * DD + col] = o;
                }
            }
        }
    }
}

// ---------------- SpMM with fp8 x-gather (256 B/row), 2 edges per wave-instr ----------
__global__ __launch_bounds__(256) void spmm_f8(
    const int* __restrict__ rp, const int2* __restrict__ spair,
    const unsigned char* __restrict__ x, unsigned short* __restrict__ y, int N)
{
    int r = blockIdx.x * 4 + (threadIdx.x >> 6);
    if (r >= N) return;
    int lane = threadIdx.x & 63;
    int half = lane >> 5;
    int hl = lane & 31;
    int s = rp[r], e = rp[r + 1];
    float acc[8];
    #pragma unroll
    for (int k = 0; k < 8; ++k) acc[k] = 0.f;
    int j = s;
    for (; j + 4 <= e; j += 4) {
        int2 pA = spair[j + half];
        int2 pB = spair[j + 2 + half];
        uint2 ua = *(const uint2*)(x + (size_t)pA.x * DD + hl * 8);
        uint2 ub = *(const uint2*)(x + (size_t)pB.x * DD + hl * 8);
        float va = __int_as_float(pA.y), vb = __int_as_float(pB.y);
        float xa[8], xb[8];
        f8x8_to_f32(ua, xa);
        f8x8_to_f32(ub, xb);
        #pragma unroll
        for (int k = 0; k < 8; ++k) acc[k] += va * xa[k] + vb * xb[k];
    }
    for (; j + 2 <= e; j += 2) {
        int2 p = spair[j + half];
        uint2 ua = *(const uint2*)(x + (size_t)p.x * DD + hl * 8);
        float v = __int_as_float(p.y);
        float xa[8];
        f8x8_to_f32(ua, xa);
        #pragma unroll
        for (int k = 0; k < 8; ++k) acc[k] += v * xa[k];
    }
    if (j < e && half == 0) {
        int2 p = spair[j];
        uint2 ua = *(const uint2*)(x + (size_t)p.x * DD + hl * 8);
        float v = __int_as_float(p.y);
        float xa[8];
        f8x8_to_f32(ua, xa);
        #pragma unroll
        for (int k = 0; k < 8; ++k) acc[k] += v * xa[k];
    }
    #pragma unroll
    for (int k = 0; k < 8; ++k) acc[k] += __shfl_xor(acc[k], 32, 64);
    if (half == 0) {
        short8 o;
        #pragma unroll
        for (int k = 0; k < 8; ++k) o[k] = (short)f2b(acc[k]);
        *(short8*)(y + (size_t)r * DD + hl * 8) = o;
    }
}

// ---------------- SpMM at target slots (bf16 gather, per-rel) ----------------
__global__ __launch_bounds__(256) void spmm_tgt_bf(
    const int* __restrict__ rp, const int2* __restrict__ spair,
    const unsigned short* __restrict__ x, const int* __restrict__ tgt,
    unsigned short* __restrict__ y, int T)
{
    int sI = blockIdx.x * 4 + (threadIdx.x >> 6);
    if (sI >= T) return;
    int lane = threadIdx.x & 63;
    int half = lane >> 5;
    int hl = lane & 31;
    int r = tgt[sI];
    int s = rp[r], e = rp[r + 1];
    float acc[8];
    #pragma unroll
    for (int k = 0; k < 8; ++k) acc[k] = 0.f;
    int j = s;
    for (; j + 4 <= e; j += 4) {
        int2 pA = spair[j + half];
        int2 pB = spair[j + 2 + half];
        short8 xa = *(const short8*)(x + (size_t)pA.x * DD + hl * 8);
        short8 xb = *(const short8*)(x + (size_t)pB.x * DD + hl * 8);
        float va = __int_as_float(pA.y), vb = __int_as_float(pB.y);
        #pragma unroll
        for (int k = 0; k < 8; ++k) {
            acc[k] += va * b2f((unsigned short)xa[k]);
            acc[k] += vb * b2f((unsigned short)xb[k]);
        }
    }
    for (; j + 2 <= e; j += 2) {
        int2 p = spair[j + half];
        short8 xv = *(const short8*)(x + (size_t)p.x * DD + hl * 8);
        float v = __int_as_float(p.y);
        #pragma unroll
        for (int k = 0; k < 8; ++k) acc[k] += v * b2f((unsigned short)xv[k]);
    }
    if (j < e && half == 0) {
        int2 p = spair[j];
        short8 xv = *(const short8*)(x + (size_t)p.x * DD + hl * 8);
        float v = __int_as_float(p.y);
        #pragma unroll
        for (int k = 0; k < 8; ++k) acc[k] += v * b2f((unsigned short)xv[k]);
    }
    #pragma unroll
    for (int k = 0; k < 8; ++k) acc[k] += __shfl_xor(acc[k], 32, 64);
    if (half == 0) {
        short8 o;
        #pragma unroll
        for (int k = 0; k < 8; ++k) o[k] = (short)f2b(acc[k]);
        *(short8*)(y + (size_t)sI * DD + hl * 8) = o;
    }
}

// ---------------- attention fuse + final LN at target slots (bf16 emb) ----------------
__global__ __launch_bounds__(256) void final_kernel(
    const unsigned short* __restrict__ emb, size_t emb_stride,
    const unsigned short* __restrict__ xg,
    const float* __restrict__ att_w, const float* __restrict__ att_b,
    const float* __restrict__ g_fin, const float* __restrict__ be_fin,
    const int* __restrict__ tgt, float* __restrict__ out, int N, int T)
{
    int sI = blockIdx.x * 4 + (threadIdx.x >> 6);
    if (sI >= T) return;
    int lane = threadIdx.x & 63;
    int t = tgt[sI];
    float4 row;
    if (t == N - 1) {
        ushort4 xv = *(const ushort4*)(xg + (size_t)t * DD + lane * 4);
        row.x = b2f(xv.x); row.y = b2f(xv.y); row.z = b2f(xv.z); row.w = b2f(xv.w);
    } else {
        ushort4 u0 = *(const ushort4*)(emb + (size_t)sI * DD + lane * 4);
        ushort4 u1 = *(const ushort4*)(emb + emb_stride + (size_t)sI * DD + lane * 4);
        ushort4 u2 = *(const ushort4*)(emb + 2 * emb_stride + (size_t)sI * DD + lane * 4);
        float4 e0 = make_float4(b2f(u0.x), b2f(u0.y), b2f(u0.z), b2f(u0.w));
        float4 e1 = make_float4(b2f(u1.x), b2f(u1.y), b2f(u1.z), b2f(u1.w));
        float4 e2 = make_float4(b2f(u2.x), b2f(u2.y), b2f(u2.z), b2f(u2.w));
        float4 aw = *(const float4*)(att_w + lane * 4);
        float s0 = e0.x*aw.x + e0.y*aw.y + e0.z*aw.z + e0.w*aw.w;
        float s1 = e1.x*aw.x + e1.y*aw.y + e1.z*aw.z + e1.w*aw.w;
        float s2 = e2.x*aw.x + e2.y*aw.y + e2.z*aw.z + e2.w*aw.w;
        #pragma unroll
        for (int off = 32; off > 0; off >>= 1) {
            s0 += __shfl_xor(s0, off, 64);
            s1 += __shfl_xor(s1, off, 64);
            s2 += __shfl_xor(s2, off, 64);
        }
        float ab = att_b[0];
        s0 += ab; s1 += ab; s2 += ab;
        float m = fmaxf(s0, fmaxf(s1, s2));
        float w0 = expf(s0 - m), w1 = expf(s1 - m), w2 = expf(s2 - m);
        float inv = 1.0f / (w0 + w1 + w2);
        w0 *= inv; w1 *= inv; w2 *= inv;
        row.x = w0*e0.x + w1*e1.x + w2*e2.x;
        row.y = w0*e0.y + w1*e1.y + w2*e2.y;
        row.z = w0*e0.z + w1*e1.z + w2*e2.z;
        row.w = w0*e0.w + w1*e1.w + w2*e2.w;
    }
    float s  = row.x + row.y + row.z + row.w;
    float ss = row.x*row.x + row.y*row.y + row.z*row.z + row.w*row.w;
    #pragma unroll
    for (int off = 32; off > 0; off >>= 1) {
        s  += __shfl_xor(s,  off, 64);
        ss += __shfl_xor(ss, off, 64);
    }
    float mean = s * (1.0f / DD);
    float var  = ss * (1.0f / DD) - mean * mean;
    float rstd = rsqrtf(var + 1e-5f);
    float4 gg  = *(const float4*)(g_fin  + lane * 4);
    float4 be4 = *(const float4*)(be_fin + lane * 4);
    float4 o;
    o.x = (row.x - mean) * rstd * gg.x + be4.x;
    o.y = (row.y - mean) * rstd * gg.y + be4.y;
    o.z = (row.z - mean) * rstd * gg.z + be4.z;
    o.w = (row.w - mean) * rstd * gg.w + be4.w;
    *(float4*)(out + (size_t)sI * DD + lane * 4) = o;
}

extern "C" void kernel_launch(void* const* d_in, const int* in_sizes, int n_in,
                              void* d_out, int out_size, void* d_ws, size_t ws_size,
                              hipStream_t stream) {
    const float* node_emb = (const float*)d_in[0];
    const float* W_pre  = (const float*)d_in[1];
    const float* b_pre  = (const float*)d_in[2];
    const float* g_pre  = (const float*)d_in[3];
    const float* be_pre = (const float*)d_in[4];
    const float* W_view = (const float*)d_in[5];
    const float* b_view = (const float*)d_in[6];
    const float* g_view = (const float*)d_in[7];
    const float* be_view= (const float*)d_in[8];
    const float* att_w  = (const float*)d_in[9];
    const float* att_b  = (const float*)d_in[10];
    const float* g_fin  = (const float*)d_in[11];
    const float* be_fin = (const float*)d_in[12];
    const float* vals   = (const float*)d_in[13];
    const int*   rows   = (const int*)d_in[14];
    const int*   cols   = (const int*)d_in[15];
    const int*   tgt    = (const int*)d_in[16];
    // d_in[17] = hops (2 per setup; host loop count)

    const int N   = in_sizes[0] / DD;
    const int R   = in_sizes[5] / (DD * DD);
    const int nnz = in_sizes[13] / R;
    const int T   = in_sizes[16];

    const int NB    = (N + BROWS - 1) >> BUCKET_SHIFT;
    const int nblkA = (nnz + CHUNK_A - 1) / CHUNK_A;
    const int S     = R * NB * nblkA;
    const int nchS  = (S + 1023) / 1024;

    // ---- workspace layout (~99 MB) ----
    char* ws = (char*)d_ws;
    size_t off = 0;
    auto alloc = [&](size_t bytes) -> char* {
        char* p = ws + off;
        off += (bytes + 255) & ~(size_t)255;
        return p;
    };
    int*            rp     = (int*)alloc((size_t)R * (N + 1) * 4);
    int*            psum   = (int*)alloc(1024);
    int*            bhraw  = (int*)alloc((size_t)S * 4);
    int*            bhs    = (int*)alloc((size_t)(S + 1) * 4);
    int2*           spair  = (int2*)alloc((size_t)R * nnz * 8);          // 20.4 MB
    unsigned short* xg_bf  = (unsigned short*)alloc((size_t)N * DD * 2); // 25.6 MB
    unsigned char*  xg_f8  = (unsigned char*)alloc((size_t)N * DD);      // 12.8 MB
    unsigned short* tmp_bf = (unsigned short*)alloc((size_t)N * DD * 2); // 25.6 MB
    unsigned short* ev_bf  = (unsigned short*)alloc((size_t)R * T * DD * 2); // 12.6 MB
    unsigned short* wt_bf  = (unsigned short*)alloc((size_t)(R + 1) * DD * DD * 2);
    // staged aliases tmp_bf (20.4 <= 25.6): consumed by bucket_build before hop-1.
    int2* staged = (int2*)tmp_bf;
    (void)ws_size; (void)n_in; (void)out_size;

    // ---- CSR build ----
    part_hist<<<dim3(nblkA, R), 256, 0, stream>>>(rows, bhraw, nnz, NB, nblkA);
    scan1<<<nchS, 256, 0, stream>>>(bhraw, bhs, psum, S, nchS);
    scan2<<<1, 256, 0, stream>>>(psum, bhs, S, nchS, 1);
    scan3<<<dim3((S + 255) / 256, 1), 256, 0, stream>>>(bhs, psum, S, nchS);
    part_scatter<<<dim3(nblkA, R), 256, 0, stream>>>(rows, cols, vals, bhs, staged,
                                                     nnz, NB, nblkA);
    bucket_build<<<dim3(NB, R), 512, 0, stream>>>(staged, bhs, rp, spair,
                                                  nnz, N, NB, nblkA, R);

    // ---- W^T bf16 ----
    transpose_cast_w<<<dim3(64, R + 1), 256, 0, stream>>>(W_pre, W_view, wt_bf);

    // ---- pre-encoder (fp32 A -> bf16 out) ----
    int ntiles_pre = (N + 127) / 128;
    int grid_pre = ntiles_pre < 256 ? ntiles_pre : 256;
    gemm_wlds<false, true><<<dim3(grid_pre, 1), 512, 0, stream>>>(
        node_emb, wt_bf, b_pre, g_pre, be_pre, xg_bf, N, ntiles_pre, 0, 0, 0, 0);

    // ---- cast x to fp8 for hop-1 gathers ----
    long n8 = (long)N * DD / 8;
    cast_f8<<<(int)((n8 + 255) / 256), 256, 0, stream>>>(xg_bf, xg_f8, n8);

    // ---- per relation: hop1 (fp8 gather) -> hop2 at targets (bf16) ----
    for (int v = 0; v < R; ++v) {
        const int* rpv = rp + (size_t)v * (N + 1);
        const int2* spv = spair + (size_t)v * nnz;
        spmm_f8<<<(N + 3) / 4, 256, 0, stream>>>(rpv, spv, xg_f8, tmp_bf, N);
        spmm_tgt_bf<<<(T + 3) / 4, 256, 0, stream>>>(rpv, spv, tmp_bf, tgt,
                                                     ev_bf + (size_t)v * T * DD, T);
    }

    // ---- all 3 view encoders in ONE dispatch, in-place on ev (bf16) ----
    int ntiles_v = (T + 127) / 128;
    gemm_wlds<true, true><<<dim3(ntiles_v, R), 512, 0, stream>>>(
        ev_bf, wt_bf + (size_t)DD * DD, b_view, g_view, be_view, ev_bf, T, ntiles_v,
        (size_t)T * DD * 2, (size_t)DD * DD, DD, (size_t)T * DD * 2);

    // ---- attention fuse + final LN at targets ----
    final_kernel<<<(T + 3) / 4, 256, 0, stream>>>(ev_bf, (size_t)T * DD, xg_bf,
                                                  att_w, att_b, g_fin, be_fin, tgt,
                                                  (float*)d_out, N, T);
}

// Round 18
// 297.922 us; speedup vs baseline: 1.7010x; 1.7010x over previous
//
#include <hip/hip_runtime.h>
#include <hip/hip_bf16.h>
#include <math.h>

#define DD 256
#define BUCKET_SHIFT 9      // 512 rows per bucket
#define BROWS 512
#define CHUNK_A 4096        // edges per partition block
#define CBLK_SHIFT 13

typedef __attribute__((ext_vector_type(8))) short short8;
typedef __attribute__((ext_vector_type(4))) float f32x4;
typedef __attribute__((ext_vector_type(2))) float f32x2;

__device__ __forceinline__ float gelu_exact(float x) {
    return 0.5f * x * (1.0f + erff(x * 0.70710678118654752f));
}
__device__ __forceinline__ float b2f(unsigned short u) {
    unsigned int v = ((unsigned int)u) << 16;
    return __builtin_bit_cast(float, v);
}
__device__ __forceinline__ unsigned short f2b(float f) {
    __hip_bfloat16 h = __float2bfloat16(f);   // RNE
    return __builtin_bit_cast(unsigned short, h);
}

// decode 8 fp8 (uint2) -> 8 f32 via packed HW converts (same decode path as scalar)
__device__ __forceinline__ void f8x8_to_f32(uint2 u, float* o) {
    f32x2 p0 = __builtin_amdgcn_cvt_pk_f32_fp8((int)u.x, false);
    f32x2 p1 = __builtin_amdgcn_cvt_pk_f32_fp8((int)u.x, true);
    f32x2 p2 = __builtin_amdgcn_cvt_pk_f32_fp8((int)u.y, false);
    f32x2 p3 = __builtin_amdgcn_cvt_pk_f32_fp8((int)u.y, true);
    o[0] = p0.x; o[1] = p0.y; o[2] = p1.x; o[3] = p1.y;
    o[4] = p2.x; o[5] = p2.y; o[6] = p3.x; o[7] = p3.y;
}

// ---------------- CSR build ----------------
__global__ __launch_bounds__(256) void part_hist(const int* __restrict__ rows,
                                                 int* __restrict__ bh,
                                                 int nnz, int NB, int nblkA) {
    int rel = blockIdx.y, blk = blockIdx.x;
    __shared__ int h[128];
    for (int b = threadIdx.x; b < NB; b += 256) h[b] = 0;
    __syncthreads();
    int base = blk * CHUNK_A;
    #pragma unroll
    for (int k = 0; k < CHUNK_A / 256; ++k) {
        int i = base + k * 256 + threadIdx.x;
        if (i < nnz) atomicAdd(&h[rows[(size_t)rel * nnz + i] >> BUCKET_SHIFT], 1);
    }
    __syncthreads();
    for (int b = threadIdx.x; b < NB; b += 256)
        bh[((size_t)(rel * NB + b)) * nblkA + blk] = h[b];
}

__global__ __launch_bounds__(256) void scan1(const int* __restrict__ cnt,
                                             int* __restrict__ rp, int* __restrict__ psum,
                                             int N, int nchunks) {
    int rel = blockIdx.x / nchunks;
    int chunk = blockIdx.x % nchunks;
    const int* c = cnt + (size_t)rel * N;
    int* out = rp + (size_t)rel * (N + 1);
    int tid = threadIdx.x, lane = tid & 63, wv = tid >> 6;
    __shared__ int wsum[4];
    int base = chunk * 1024 + tid * 4;
    int v[4];
    if (base + 3 < N) {
        int4 t4 = *(const int4*)(c + base);
        v[0] = t4.x; v[1] = t4.y; v[2] = t4.z; v[3] = t4.w;
    } else {
        #pragma unroll
        for (int q = 0; q < 4; ++q) v[q] = (base + q < N) ? c[base + q] : 0;
    }
    int tsum = v[0] + v[1] + v[2] + v[3];
    int x = tsum;
    #pragma unroll
    for (int off = 1; off < 64; off <<= 1) {
        int t = __shfl_up(x, off, 64);
        if (lane >= off) x += t;
    }
    if (lane == 63) wsum[wv] = x;
    __syncthreads();
    int woff = 0;
    #pragma unroll
    for (int k = 0; k < 4; ++k) if (k < wv) woff += wsum[k];
    int run = woff + x - tsum;
    #pragma unroll
    for (int q = 0; q < 4; ++q) {
        if (base + q < N) out[base + q] = run;
        run += v[q];
    }
    if (tid == 255) psum[rel * nchunks + chunk] = woff + x;
}

__global__ __launch_bounds__(256) void scan2(int* __restrict__ psum, int* __restrict__ rp,
                                             int N, int nchunks, int R) {
    int rel = threadIdx.x >> 6, lane = threadIdx.x & 63;
    if (rel >= R) return;
    int v = (lane < nchunks) ? psum[rel * nchunks + lane] : 0;
    int x = v;
    #pragma unroll
    for (int off = 1; off < 64; off <<= 1) {
        int t = __shfl_up(x, off, 64);
        if (lane >= off) x += t;
    }
    if (lane < nchunks) psum[rel * nchunks + lane] = x - v;
    if (lane == 63) rp[(size_t)rel * (N + 1) + N] = x;
}

__global__ __launch_bounds__(256) void scan3(int* __restrict__ rp, const int* __restrict__ psum,
                                             int N, int nchunks) {
    int rel = blockIdx.y;
    int i = blockIdx.x * 256 + threadIdx.x;
    if (i >= N) return;
    rp[(size_t)rel * (N + 1) + i] += psum[rel * nchunks + (i >> 10)];
}

__global__ __launch_bounds__(256) void part_scatter(
    const int* __restrict__ rows, const int* __restrict__ cols,
    const float* __restrict__ vals, const int* __restrict__ bhs,
    int2* __restrict__ staged, int nnz, int NB, int nblkA) {
    int rel = blockIdx.y, blk = blockIdx.x;
    __shared__ int cur[128];
    for (int b = threadIdx.x; b < NB; b += 256)
        cur[b] = bhs[((size_t)(rel * NB + b)) * nblkA + blk];
    __syncthreads();
    int base = blk * CHUNK_A;
    #pragma unroll
    for (int k = 0; k < CHUNK_A / 256; ++k) {
        int i = base + k * 256 + threadIdx.x;
        if (i < nnz) {
            int r = rows[(size_t)rel * nnz + i];
            unsigned c = (unsigned)cols[(size_t)rel * nnz + i];
            float v = vals[(size_t)rel * nnz + i];
            int pos = atomicAdd(&cur[r >> BUCKET_SHIFT], 1);
            int2 pr;
            pr.x = (int)(((unsigned)r << 16) | c);
            pr.y = __float_as_int(v);
            staged[pos] = pr;
        }
    }
}

// single-pass (row x colblock) counting sort (r13, verified)
__global__ __launch_bounds__(512) void bucket_build(
    const int2* __restrict__ staged, const int* __restrict__ bhs,
    int* __restrict__ rp, int2* __restrict__ spair,
    int nnz, int N, int NB, int nblkA, int R) {
    int rel = blockIdx.y, b = blockIdx.x;
    int start = bhs[((size_t)(rel * NB + b)) * nblkA];
    int nb1 = rel * NB + b + 1;
    int end = (nb1 < R * NB) ? bhs[(size_t)nb1 * nblkA] : R * nnz;
    int csr_base = start - rel * nnz;
    int rowbase = b << BUCKET_SHIFT;
    __shared__ int cnt2[BROWS * 8];
    __shared__ int wsum[8];
    int t = threadIdx.x, lane = t & 63, wv = t >> 6;
    #pragma unroll
    for (int q = 0; q < 8; ++q) cnt2[t + q * BROWS] = 0;
    __syncthreads();
    for (int i = start + t; i < end; i += 512) {
        unsigned p = (unsigned)staged[i].x;
        int rb = (int)(p >> 16) - rowbase;
        int cb = (int)(p & 0xFFFFu) >> CBLK_SHIFT;
        atomicAdd(&cnt2[rb * 8 + cb], 1);
    }
    __syncthreads();
    int c[8];
    int v = 0;
    #pragma unroll
    for (int q = 0; q < 8; ++q) { c[q] = cnt2[t * 8 + q]; v += c[q]; }
    int x = v;
    #pragma unroll
    for (int off = 1; off < 64; off <<= 1) {
        int tt = __shfl_up(x, off, 64);
        if (lane >= off) x += tt;
    }
    if (lane == 63) wsum[wv] = x;
    __syncthreads();
    int woff = 0;
    #pragma unroll
    for (int k = 0; k < 8; ++k) if (k < wv) woff += wsum[k];
    int excl = woff + x - v;
    __syncthreads();
    int run = excl;
    #pragma unroll
    for (int q = 0; q < 8; ++q) { cnt2[t * 8 + q] = run; run += c[q]; }
    int gr = rowbase + t;
    if (gr <= N) rp[(size_t)rel * (N + 1) + gr] = csr_base + excl;
    __syncthreads();
    for (int i = start + t; i < end; i += 512) {
        int2 s = staged[i];
        unsigned p = (unsigned)s.x;
        int rb = (int)(p >> 16) - rowbase;
        int col = (int)(p & 0xFFFFu);
        int pos = atomicAdd(&cnt2[rb * 8 + (col >> CBLK_SHIFT)], 1);
        int2 pr;
        pr.x = col;
        pr.y = s.y;
        spair[(size_t)rel * nnz + csr_base + pos] = pr;
    }
}

// ---------------- tiled W transpose+cast ----------------
__global__ __launch_bounds__(256) void transpose_cast_w(
    const float* __restrict__ Wp, const float* __restrict__ Wv,
    unsigned short* __restrict__ wt) {
    __shared__ float tile[32][33];
    int m = blockIdx.y;
    int tb = blockIdx.x;
    int k0 = (tb & 7) * 32, n0 = (tb >> 3) * 32;
    const float* W = (m == 0) ? Wp : (Wv + (size_t)(m - 1) * 65536);
    int tx = threadIdx.x & 31, ty = threadIdx.x >> 5;
    #pragma unroll
    for (int i = 0; i < 4; ++i)
        tile[ty + 8 * i][tx] = W[(size_t)(k0 + ty + 8 * i) * 256 + n0 + tx];
    __syncthreads();
    #pragma unroll
    for (int i = 0; i < 4; ++i)
        wt[(size_t)m * 65536 + (size_t)(n0 + ty + 8 * i) * 256 + k0 + tx] =
            f2b(tile[tx][ty + 8 * i]);
}

// ---------------- bf16 -> fp8 e4m3 cast (HW RNE via v_cvt_pk_fp8_f32) ----------------
__global__ __launch_bounds__(256) void cast_f8(const unsigned short* __restrict__ xb,
                                               unsigned char* __restrict__ xf, long n8) {
    long i = (long)blockIdx.x * 256 + threadIdx.x;   // 8 elems per thread
    if (i >= n8) return;
    short8 v = *(const short8*)(xb + i * 8);
    float f[8];
    #pragma unroll
    for (int k = 0; k < 8; ++k) f[k] = b2f((unsigned short)v[k]);
    int d0 = __builtin_amdgcn_cvt_pk_fp8_f32(f[0], f[1], 0, false);
    d0 = __builtin_amdgcn_cvt_pk_fp8_f32(f[2], f[3], d0, true);
    int d1 = __builtin_amdgcn_cvt_pk_fp8_f32(f[4], f[5], 0, false);
    d1 = __builtin_amdgcn_cvt_pk_fp8_f32(f[6], f[7], d1, true);
    *(uint2*)(xf + i * 8) = make_uint2((unsigned)d0, (unsigned)d1);
}

// ---------------- W-in-LDS MFMA GEMM -> LN -> GELU (512 threads, r16 body) ----------
// __launch_bounds__(512, 2): 1 block/CU (128 KB LDS) = 2 waves/SIMD is the real
// occupancy, so declare it -> register allocator budget 256 VGPR (r17's implicit
// 128-cap caused scratch spills). Body identical to the verified r16 kernel.
template <bool A_BF16, bool OUT_BF16>
__global__ __launch_bounds__(512, 2) void gemm_wlds(
    const void* __restrict__ Aptr, const unsigned short* __restrict__ Wt,
    const float* __restrict__ bias, const float* __restrict__ gamma,
    const float* __restrict__ beta, void* __restrict__ outp, int M, int ntiles,
    size_t aStrideB, size_t wStride, int pStride, size_t oStrideB)
{
    __shared__ __align__(16) unsigned short Wl[256 * 256];
    __shared__ float Pb[DD], Pg[DD], Pe[DD];
    const int rel = blockIdx.y;
    const char* Abase = (const char*)Aptr + (size_t)rel * aStrideB;
    char* Obase = (char*)outp + (size_t)rel * oStrideB;
    const unsigned short* Wtr = Wt + (size_t)rel * wStride;
    const int tid = threadIdx.x;
    const int lane = tid & 63;
    const int wv = tid >> 6;
    if (tid < DD) {
        Pb[tid] = bias[rel * pStride + tid];
        Pg[tid] = gamma[rel * pStride + tid];
        Pe[tid] = beta[rel * pStride + tid];
    }
    {
        int n = tid >> 1;
        int half = tid & 1;
        const unsigned short* src = Wtr + (size_t)n * DD + half * 128;
        #pragma unroll
        for (int c = 0; c < 16; ++c) {
            int c16 = half * 16 + c;
            short8 v = *(const short8*)(src + c * 8);
            *(short8*)(Wl + n * DD + ((c16 ^ (n & 7)) << 3)) = v;
        }
    }
    __syncthreads();

    const int cl = lane & 15, g = lane >> 4;

    for (int tile = blockIdx.x; tile < ntiles; tile += gridDim.x) {
        const int rbase = tile * 128 + wv * 16;
        const int arow = rbase + cl;
        const bool rok = arow < M;
        f32x4 acc[16];
        #pragma unroll
        for (int j = 0; j < 16; ++j) acc[j] = (f32x4){0.f, 0.f, 0.f, 0.f};

        #pragma unroll 2
        for (int ks = 0; ks < 8; ++ks) {
            short8 af = (short8){0,0,0,0,0,0,0,0};
            if (rok) {
                if (A_BF16) {
                    af = *(const short8*)((const unsigned short*)Abase +
                            (size_t)arow * DD + ks * 32 + g * 8);
                } else {
                    const float* ap = (const float*)Abase + (size_t)arow * DD + ks * 32 + g * 8;
                    float4 f0 = *(const float4*)ap;
                    float4 f1 = *(const float4*)(ap + 4);
                    af = (short8){(short)f2b(f0.x), (short)f2b(f0.y), (short)f2b(f0.z), (short)f2b(f0.w),
                                  (short)f2b(f1.x), (short)f2b(f1.y), (short)f2b(f1.z), (short)f2b(f1.w)};
                }
            }
            int c16 = 4 * ks + g;
            #pragma unroll
            for (int j = 0; j < 16; ++j) {
                int n = j * 16 + cl;
                short8 bf = *(const short8*)(Wl + n * DD + ((c16 ^ (n & 7)) << 3));
                acc[j] = __builtin_amdgcn_mfma_f32_16x16x32_bf16(af, bf, acc[j], 0, 0, 0);
            }
        }

        #pragma unroll
        for (int q = 0; q < 4; ++q) {
            float yv[16];
            float s = 0.f, ss = 0.f;
            #pragma unroll
            for (int j = 0; j < 16; ++j) {
                float y = acc[j][q] + Pb[cl + 16 * j];
                yv[j] = y; s += y; ss += y * y;
            }
            #pragma unroll
            for (int off = 1; off < 16; off <<= 1) {
                s  += __shfl_xor(s,  off, 16);
                ss += __shfl_xor(ss, off, 16);
            }
            float mean = s * (1.0f / DD);
            float var  = ss * (1.0f / DD) - mean * mean;
            float rstd = rsqrtf(var + 1e-5f);
            int row = rbase + g * 4 + q;
            if (row < M) {
                #pragma unroll
                for (int j = 0; j < 16; ++j) {
                    int col = cl + 16 * j;
                    float o = gelu_exact((yv[j] - mean) * rstd * Pg[col] + Pe[col]);
                    if (OUT_BF16)
                        ((unsigned short*)Obase)[(size_t)row * DD + col] = f2b(o);
                    else
                        ((float*)Obase)[(size_t)row * DD + col] = o;
                }
            }
        }
    }
}

// ---------------- SpMM with fp8 x-gather (256 B/row), 2 edges per wave-instr ----------
__global__ __launch_bounds__(256) void spmm_f8(
    const int* __restrict__ rp, const int2* __restrict__ spair,
    const unsigned char* __restrict__ x, unsigned short* __restrict__ y, int N)
{
    int r = blockIdx.x * 4 + (threadIdx.x >> 6);
    if (r >= N) return;
    int lane = threadIdx.x & 63;
    int half = lane >> 5;
    int hl = lane & 31;
    int s = rp[r], e = rp[r + 1];
    float acc[8];
    #pragma unroll
    for (int k = 0; k < 8; ++k) acc[k] = 0.f;
    int j = s;
    for (; j + 4 <= e; j += 4) {
        int2 pA = spair[j + half];
        int2 pB = spair[j + 2 + half];
        uint2 ua = *(const uint2*)(x + (size_t)pA.x * DD + hl * 8);
        uint2 ub = *(const uint2*)(x + (size_t)pB.x * DD + hl * 8);
        float va = __int_as_float(pA.y), vb = __int_as_float(pB.y);
        float xa[8], xb[8];
        f8x8_to_f32(ua, xa);
        f8x8_to_f32(ub, xb);
        #pragma unroll
        for (int k = 0; k < 8; ++k) acc[k] += va * xa[k] + vb * xb[k];
    }
    for (; j + 2 <= e; j += 2) {
        int2 p = spair[j + half];
        uint2 ua = *(const uint2*)(x + (size_t)p.x * DD + hl * 8);
        float v = __int_as_float(p.y);
        float xa[8];
        f8x8_to_f32(ua, xa);
        #pragma unroll
        for (int k = 0; k < 8; ++k) acc[k] += v * xa[k];
    }
    if (j < e && half == 0) {
        int2 p = spair[j];
        uint2 ua = *(const uint2*)(x + (size_t)p.x * DD + hl * 8);
        float v = __int_as_float(p.y);
        float xa[8];
        f8x8_to_f32(ua, xa);
        #pragma unroll
        for (int k = 0; k < 8; ++k) acc[k] += v * xa[k];
    }
    #pragma unroll
    for (int k = 0; k < 8; ++k) acc[k] += __shfl_xor(acc[k], 32, 64);
    if (half == 0) {
        short8 o;
        #pragma unroll
        for (int k = 0; k < 8; ++k) o[k] = (short)f2b(acc[k]);
        *(short8*)(y + (size_t)r * DD + hl * 8) = o;
    }
}

// ---------------- SpMM at target slots (bf16 gather, per-rel) ----------------
__global__ __launch_bounds__(256) void spmm_tgt_bf(
    const int* __restrict__ rp, const int2* __restrict__ spair,
    const unsigned short* __restrict__ x, const int* __restrict__ tgt,
    unsigned short* __restrict__ y, int T)
{
    int sI = blockIdx.x * 4 + (threadIdx.x >> 6);
    if (sI >= T) return;
    int lane = threadIdx.x & 63;
    int half = lane >> 5;
    int hl = lane & 31;
    int r = tgt[sI];
    int s = rp[r], e = rp[r + 1];
    float acc[8];
    #pragma unroll
    for (int k = 0; k < 8; ++k) acc[k] = 0.f;
    int j = s;
    for (; j + 4 <= e; j += 4) {
        int2 pA = spair[j + half];
        int2 pB = spair[j + 2 + half];
        short8 xa = *(const short8*)(x + (size_t)pA.x * DD + hl * 8);
        short8 xb = *(const short8*)(x + (size_t)pB.x * DD + hl * 8);
        float va = __int_as_float(pA.y), vb = __int_as_float(pB.y);
        #pragma unroll
        for (int k = 0; k < 8; ++k) {
            acc[k] += va * b2f((unsigned short)xa[k]);
            acc[k] += vb * b2f((unsigned short)xb[k]);
        }
    }
    for (; j + 2 <= e; j += 2) {
        int2 p = spair[j + half];
        short8 xv = *(const short8*)(x + (size_t)p.x * DD + hl * 8);
        float v = __int_as_float(p.y);
        #pragma unroll
        for (int k = 0; k < 8; ++k) acc[k] += v * b2f((unsigned short)xv[k]);
    }
    if (j < e && half == 0) {
        int2 p = spair[j];
        short8 xv = *(const short8*)(x + (size_t)p.x * DD + hl * 8);
        float v = __int_as_float(p.y);
        #pragma unroll
        for (int k = 0; k < 8; ++k) acc[k] += v * b2f((unsigned short)xv[k]);
    }
    #pragma unroll
    for (int k = 0; k < 8; ++k) acc[k] += __shfl_xor(acc[k], 32, 64);
    if (half == 0) {
        short8 o;
        #pragma unroll
        for (int k = 0; k < 8; ++k) o[k] = (short)f2b(acc[k]);
        *(short8*)(y + (size_t)sI * DD + hl * 8) = o;
    }
}

// ---------------- attention fuse + final LN at target slots (bf16 emb) ----------------
__global__ __launch_bounds__(256) void final_kernel(
    const unsigned short* __restrict__ emb, size_t emb_stride,
    const unsigned short* __restrict__ xg,
    const float* __restrict__ att_w, const float* __restrict__ att_b,
    const float* __restrict__ g_fin, const float* __restrict__ be_fin,
    const int* __restrict__ tgt, float* __restrict__ out, int N, int T)
{
    int sI = blockIdx.x * 4 + (threadIdx.x >> 6);
    if (sI >= T) return;
    int lane = threadIdx.x & 63;
    int t = tgt[sI];
    float4 row;
    if (t == N - 1) {
        ushort4 xv = *(const ushort4*)(xg + (size_t)t * DD + lane * 4);
        row.x = b2f(xv.x); row.y = b2f(xv.y); row.z = b2f(xv.z); row.w = b2f(xv.w);
    } else {
        ushort4 u0 = *(const ushort4*)(emb + (size_t)sI * DD + lane * 4);
        ushort4 u1 = *(const ushort4*)(emb + emb_stride + (size_t)sI * DD + lane * 4);
        ushort4 u2 = *(const ushort4*)(emb + 2 * emb_stride + (size_t)sI * DD + lane * 4);
        float4 e0 = make_float4(b2f(u0.x), b2f(u0.y), b2f(u0.z), b2f(u0.w));
        float4 e1 = make_float4(b2f(u1.x), b2f(u1.y), b2f(u1.z), b2f(u1.w));
        float4 e2 = make_float4(b2f(u2.x), b2f(u2.y), b2f(u2.z), b2f(u2.w));
        float4 aw = *(const float4*)(att_w + lane * 4);
        float s0 = e0.x*aw.x + e0.y*aw.y + e0.z*aw.z + e0.w*aw.w;
        float s1 = e1.x*aw.x + e1.y*aw.y + e1.z*aw.z + e1.w*aw.w;
        float s2 = e2.x*aw.x + e2.y*aw.y + e2.z*aw.z + e2.w*aw.w;
        #pragma unroll
        for (int off = 32; off > 0; off >>= 1) {
            s0 += __shfl_xor(s0, off, 64);
            s1 += __shfl_xor(s1, off, 64);
            s2 += __shfl_xor(s2, off, 64);
        }
        float ab = att_b[0];
        s0 += ab; s1 += ab; s2 += ab;
        float m = fmaxf(s0, fmaxf(s1, s2));
        float w0 = expf(s0 - m), w1 = expf(s1 - m), w2 = expf(s2 - m);
        float inv = 1.0f / (w0 + w1 + w2);
        w0 *= inv; w1 *= inv; w2 *= inv;
        row.x = w0*e0.x + w1*e1.x + w2*e2.x;
        row.y = w0*e0.y + w1*e1.y + w2*e2.y;
        row.z = w0*e0.z + w1*e1.z + w2*e2.z;
        row.w = w0*e0.w + w1*e1.w + w2*e2.w;
    }
    float s  = row.x + row.y + row.z + row.w;
    float ss = row.x*row.x + row.y*row.y + row.z*row.z + row.w*row.w;
    #pragma unroll
    for (int off = 32; off > 0; off >>= 1) {
        s  += __shfl_xor(s,  off, 64);
        ss += __shfl_xor(ss, off, 64);
    }
    float mean = s * (1.0f / DD);
    float var  = ss * (1.0f / DD) - mean * mean;
    float rstd = rsqrtf(var + 1e-5f);
    float4 gg  = *(const float4*)(g_fin  + lane * 4);
    float4 be4 = *(const float4*)(be_fin + lane * 4);
    float4 o;
    o.x = (row.x - mean) * rstd * gg.x + be4.x;
    o.y = (row.y - mean) * rstd * gg.y + be4.y;
    o.z = (row.z - mean) * rstd * gg.z + be4.z;
    o.w = (row.w - mean) * rstd * gg.w + be4.w;
    *(float4*)(out + (size_t)sI * DD + lane * 4) = o;
}

extern "C" void kernel_launch(void* const* d_in, const int* in_sizes, int n_in,
                              void* d_out, int out_size, void* d_ws, size_t ws_size,
                              hipStream_t stream) {
    const float* node_emb = (const float*)d_in[0];
    const float* W_pre  = (const float*)d_in[1];
    const float* b_pre  = (const float*)d_in[2];
    const float* g_pre  = (const float*)d_in[3];
    const float* be_pre = (const float*)d_in[4];
    const float* W_view = (const float*)d_in[5];
    const float* b_view = (const float*)d_in[6];
    const float* g_view = (const float*)d_in[7];
    const float* be_view= (const float*)d_in[8];
    const float* att_w  = (const float*)d_in[9];
    const float* att_b  = (const float*)d_in[10];
    const float* g_fin  = (const float*)d_in[11];
    const float* be_fin = (const float*)d_in[12];
    const float* vals   = (const float*)d_in[13];
    const int*   rows   = (const int*)d_in[14];
    const int*   cols   = (const int*)d_in[15];
    const int*   tgt    = (const int*)d_in[16];
    // d_in[17] = hops (2 per setup; host loop count)

    const int N   = in_sizes[0] / DD;
    const int R   = in_sizes[5] / (DD * DD);
    const int nnz = in_sizes[13] / R;
    const int T   = in_sizes[16];

    const int NB    = (N + BROWS - 1) >> BUCKET_SHIFT;
    const int nblkA = (nnz + CHUNK_A - 1) / CHUNK_A;
    const int S     = R * NB * nblkA;
    const int nchS  = (S + 1023) / 1024;

    // ---- workspace layout (~99 MB) ----
    char* ws = (char*)d_ws;
    size_t off = 0;
    auto alloc = [&](size_t bytes) -> char* {
        char* p = ws + off;
        off += (bytes + 255) & ~(size_t)255;
        return p;
    };
    int*            rp     = (int*)alloc((size_t)R * (N + 1) * 4);
    int*            psum   = (int*)alloc(1024);
    int*            bhraw  = (int*)alloc((size_t)S * 4);
    int*            bhs    = (int*)alloc((size_t)(S + 1) * 4);
    int2*           spair  = (int2*)alloc((size_t)R * nnz * 8);          // 20.4 MB
    unsigned short* xg_bf  = (unsigned short*)alloc((size_t)N * DD * 2); // 25.6 MB
    unsigned char*  xg_f8  = (unsigned char*)alloc((size_t)N * DD);      // 12.8 MB
    unsigned short* tmp_bf = (unsigned short*)alloc((size_t)N * DD * 2); // 25.6 MB
    unsigned short* ev_bf  = (unsigned short*)alloc((size_t)R * T * DD * 2); // 12.6 MB
    unsigned short* wt_bf  = (unsigned short*)alloc((size_t)(R + 1) * DD * DD * 2);
    // staged aliases tmp_bf (20.4 <= 25.6): consumed by bucket_build before hop-1.
    int2* staged = (int2*)tmp_bf;
    (void)ws_size; (void)n_in; (void)out_size;

    // ---- CSR build ----
    part_hist<<<dim3(nblkA, R), 256, 0, stream>>>(rows, bhraw, nnz, NB, nblkA);
    scan1<<<nchS, 256, 0, stream>>>(bhraw, bhs, psum, S, nchS);
    scan2<<<1, 256, 0, stream>>>(psum, bhs, S, nchS, 1);
    scan3<<<dim3((S + 255) / 256, 1), 256, 0, stream>>>(bhs, psum, S, nchS);
    part_scatter<<<dim3(nblkA, R), 256, 0, stream>>>(rows, cols, vals, bhs, staged,
                                                     nnz, NB, nblkA);
    bucket_build<<<dim3(NB, R), 512, 0, stream>>>(staged, bhs, rp, spair,
                                                  nnz, N, NB, nblkA, R);

    // ---- W^T bf16 ----
    transpose_cast_w<<<dim3(64, R + 1), 256, 0, stream>>>(W_pre, W_view, wt_bf);

    // ---- pre-encoder (fp32 A -> bf16 out) ----
    int ntiles_pre = (N + 127) / 128;
    int grid_pre = ntiles_pre < 256 ? ntiles_pre : 256;
    gemm_wlds<false, true><<<dim3(grid_pre, 1), 512, 0, stream>>>(
        node_emb, wt_bf, b_pre, g_pre, be_pre, xg_bf, N, ntiles_pre, 0, 0, 0, 0);

    // ---- cast x to fp8 for hop-1 gathers ----
    long n8 = (long)N * DD / 8;
    cast_f8<<<(int)((n8 + 255) / 256), 256, 0, stream>>>(xg_bf, xg_f8, n8);

    // ---- per relation: hop1 (fp8 gather) -> hop2 at targets (bf16) ----
    for (int v = 0; v < R; ++v) {
        const int* rpv = rp + (size_t)v * (N + 1);
        const int2* spv = spair + (size_t)v * nnz;
        spmm_f8<<<(N + 3) / 4, 256, 0, stream>>>(rpv, spv, xg_f8, tmp_bf, N);
        spmm_tgt_bf<<<(T + 3) / 4, 256, 0, stream>>>(rpv, spv, tmp_bf, tgt,
                                                     ev_bf + (size_t)v * T * DD, T);
    }

    // ---- all 3 view encoders in ONE dispatch, in-place on ev (bf16) ----
    int ntiles_v = (T + 127) / 128;
    gemm_wlds<true, true><<<dim3(ntiles_v, R), 512, 0, stream>>>(
        ev_bf, wt_bf + (size_t)DD * DD, b_view, g_view, be_view, ev_bf, T, ntiles_v,
        (size_t)T * DD * 2, (size_t)DD * DD, DD, (size_t)T * DD * 2);

    // ---- attention fuse + final LN at targets ----
    final_kernel<<<(T + 3) / 4, 256, 0, stream>>>(ev_bf, (size_t)T * DD, xg_bf,
                                                  att_w, att_b, g_fin, be_fin, tgt,
                                                  (float*)d_out, N, T);
}